// Round 9
// baseline (132.471 us; speedup 1.0000x reference)
//
#include <hip/hip_runtime.h>
#include <hip/hip_bf16.h>

#define NN 6144
#define IN_DIM 256
#define HID 64
#define HEADS 4
#define LAT 32
#define CAP 192
#define ALPHA 0.2f

typedef __attribute__((ext_vector_type(8))) short bf16x8;
typedef __attribute__((ext_vector_type(4))) float f32x4;

__device__ __forceinline__ float elu_f(float v)   { return v > 0.f ? v : expm1f(v); }
__device__ __forceinline__ float lrelu_f(float v) { return v > 0.f ? v : ALPHA * v; }

__device__ __forceinline__ void split_bf16(float v, unsigned short& hi, unsigned short& lo) {
    unsigned u = __builtin_bit_cast(unsigned, v);
    hi = (unsigned short)(u >> 16);
    float vh = __builtin_bit_cast(float, u & 0xFFFF0000u);
    float rl = v - vh;                       // exact
    lo = (unsigned short)(__builtin_bit_cast(unsigned, rl) >> 16);
}

// ---------------- k_gemm1: Wh = x @ W_heads, fused es/ed epilogue ----------------
__global__ __launch_bounds__(256) void k_gemm1(const float* __restrict__ x,
                                               const float* __restrict__ Wheads,
                                               const float* __restrict__ aheads,
                                               float* __restrict__ Wh,
                                               float* __restrict__ es, float* __restrict__ ed) {
    __shared__ float As[16][64];
    __shared__ float Bs[16][64];
    int head = blockIdx.x & 3, m0 = (blockIdx.x >> 2) * 64;
    const float* Wc = Wheads + (size_t)head * IN_DIM * HID;
    int t = threadIdx.x;
    int ty = t >> 4, tx = t & 15;
    float acc[4][4] = {};
    for (int k0 = 0; k0 < IN_DIM; k0 += 16) {
        {
            int row = t >> 2, k4 = (t & 3) * 4;
            float4 v = *(const float4*)(x + (size_t)(m0 + row) * IN_DIM + k0 + k4);
            As[k4 + 0][row] = v.x; As[k4 + 1][row] = v.y;
            As[k4 + 2][row] = v.z; As[k4 + 3][row] = v.w;
            int kk = t >> 4, n4 = (t & 15) * 4;
            *(float4*)&Bs[kk][n4] = *(const float4*)(Wc + (size_t)(k0 + kk) * HID + n4);
        }
        __syncthreads();
        #pragma unroll
        for (int k = 0; k < 16; ++k) {
            float4 av = *(float4*)&As[k][ty * 4];
            float4 bv = *(float4*)&Bs[k][tx * 4];
            float ar[4] = {av.x, av.y, av.z, av.w};
            float br[4] = {bv.x, bv.y, bv.z, bv.w};
            #pragma unroll
            for (int i = 0; i < 4; ++i)
                #pragma unroll
                for (int j = 0; j < 4; ++j)
                    acc[i][j] = fmaf(ar[i], br[j], acc[i][j]);
        }
        __syncthreads();
    }
    #pragma unroll
    for (int i = 0; i < 4; ++i) {
        float4 o = make_float4(acc[i][0], acc[i][1], acc[i][2], acc[i][3]);
        *(float4*)(Wh + (size_t)(m0 + ty * 4 + i) * (HEADS * HID) + head * HID + tx * 4) = o;
    }
    float4 a1v = *(const float4*)(aheads + head * 2 * HID + tx * 4);
    float4 a2v = *(const float4*)(aheads + head * 2 * HID + HID + tx * 4);
    #pragma unroll
    for (int i = 0; i < 4; ++i) {
        float p1 = acc[i][0] * a1v.x + acc[i][1] * a1v.y + acc[i][2] * a1v.z + acc[i][3] * a1v.w;
        float p2 = acc[i][0] * a2v.x + acc[i][1] * a2v.y + acc[i][2] * a2v.z + acc[i][3] * a2v.w;
        #pragma unroll
        for (int off = 8; off; off >>= 1) {
            p1 += __shfl_down(p1, off, 16);
            p2 += __shfl_down(p2, off, 16);
        }
        if (tx == 0) {
            es[head * NN + m0 + ty * 4 + i] = p1;
            ed[head * NN + m0 + ty * 4 + i] = p2;
        }
    }
}

// ---------------- k_rowattn: A-row scan + attention layer 1 + fused gemm2/e2 ----------------
// One block per row i. Streams A[i,:] (HBM) to build the neighbor list in LDS,
// overlapping (across resident blocks) with the L2/L3 gather phases below.
__global__ __launch_bounds__(256, 8) void k_rowattn(const float* __restrict__ A,
                                                    int* __restrict__ nbr, int* __restrict__ cnt,
                                                    const float* __restrict__ es, const float* __restrict__ ed,
                                                    const float* __restrict__ Wh,
                                                    const float* __restrict__ Wout, const float* __restrict__ aout,
                                                    float* __restrict__ Wh2,
                                                    float* __restrict__ es2, float* __restrict__ ed2) {
    __shared__ int colS[CAP];
    __shared__ float att[HEADS][CAP];
    __shared__ float hrow[HEADS * HID];
    __shared__ float part[8][LAT];
    __shared__ int lcnt;
    int i = blockIdx.x;
    int t = threadIdx.x, h = t >> 6, l = t & 63;

    // ---- scan own row of A ----
    if (t == 0) lcnt = 0;
    __syncthreads();
    const float4* Arow = (const float4*)(A + (size_t)i * NN);
    #pragma unroll
    for (int it = 0; it < NN / 4 / 256; ++it) {   // 6 iters
        int idx4 = it * 256 + t;
        float4 v = Arow[idx4];
        int base = idx4 * 4;
        if (v.x != 0.f) { int p = atomicAdd(&lcnt, 1); if (p < CAP) colS[p] = base; }
        if (v.y != 0.f) { int p = atomicAdd(&lcnt, 1); if (p < CAP) colS[p] = base + 1; }
        if (v.z != 0.f) { int p = atomicAdd(&lcnt, 1); if (p < CAP) colS[p] = base + 2; }
        if (v.w != 0.f) { int p = atomicAdd(&lcnt, 1); if (p < CAP) colS[p] = base + 3; }
    }
    __syncthreads();
    int c = lcnt < CAP ? lcnt : CAP;
    if (t == 0) cnt[i] = c;
    for (int j = t; j < c; j += 256) nbr[(size_t)i * CAP + j] = colS[j];   // for attn2

    // ---- attention layer 1, wave h = head h ----
    float hval;
    if (c == 0) {
        float s = 0.f;
        for (int r = 0; r < NN; ++r) s += Wh[(size_t)r * (HEADS * HID) + h * HID + l];
        hval = elu_f(s * (1.0f / NN));
    } else {
        float esi = es[h * NN + i];
        float m = -3.0e38f;
        for (int j = l; j < c; j += 64) {
            float e = lrelu_f(esi + ed[h * NN + colS[j]]);
            att[h][j] = e;
            m = fmaxf(m, e);
        }
        #pragma unroll
        for (int off = 32; off; off >>= 1) m = fmaxf(m, __shfl_down(m, off));
        m = __shfl(m, 0);
        float s = 0.f;
        for (int j = l; j < c; j += 64) {
            float p = __expf(att[h][j] - m);
            att[h][j] = p;
            s += p;
        }
        #pragma unroll
        for (int off = 32; off; off >>= 1) s += __shfl_down(s, off);
        s = __shfl(s, 0);
        __syncthreads();
        float inv = 1.0f / s;
        const float* WhH = Wh + h * HID + l;
        float a0 = 0.f, a1 = 0.f, a2 = 0.f, a3 = 0.f;
        float a4 = 0.f, a5 = 0.f, a6 = 0.f, a7 = 0.f;
        int j = 0;
        for (; j + 8 <= c; j += 8) {
            a0 = fmaf(att[h][j + 0], WhH[(size_t)colS[j + 0] * (HEADS * HID)], a0);
            a1 = fmaf(att[h][j + 1], WhH[(size_t)colS[j + 1] * (HEADS * HID)], a1);
            a2 = fmaf(att[h][j + 2], WhH[(size_t)colS[j + 2] * (HEADS * HID)], a2);
            a3 = fmaf(att[h][j + 3], WhH[(size_t)colS[j + 3] * (HEADS * HID)], a3);
            a4 = fmaf(att[h][j + 4], WhH[(size_t)colS[j + 4] * (HEADS * HID)], a4);
            a5 = fmaf(att[h][j + 5], WhH[(size_t)colS[j + 5] * (HEADS * HID)], a5);
            a6 = fmaf(att[h][j + 6], WhH[(size_t)colS[j + 6] * (HEADS * HID)], a6);
            a7 = fmaf(att[h][j + 7], WhH[(size_t)colS[j + 7] * (HEADS * HID)], a7);
        }
        for (; j < c; ++j)
            a0 = fmaf(att[h][j], WhH[(size_t)colS[j] * (HEADS * HID)], a0);
        hval = elu_f((((a0 + a1) + (a2 + a3)) + ((a4 + a5) + (a6 + a7))) * inv);
    }
    hrow[h * HID + l] = hval;
    __syncthreads();
    // ---- gemm2 row-local: Wh2[i,:] = hrow @ Wout ----
    {
        int half = l >> 5, cc = l & 31;
        int tbase = h * HID + half * 32;
        float p = 0.f;
        #pragma unroll 8
        for (int tt = 0; tt < 32; ++tt)
            p = fmaf(hrow[tbase + tt], Wout[(tbase + tt) * LAT + cc], p);
        part[h * 2 + half][cc] = p;
    }
    __syncthreads();
    if (t < 32) {
        float acc = 0.f;
        #pragma unroll
        for (int w = 0; w < 8; ++w) acc += part[w][t];
        Wh2[(size_t)i * LAT + t] = acc;
        float p1 = acc * aout[t], p2 = acc * aout[LAT + t];
        #pragma unroll
        for (int off = 16; off; off >>= 1) {
            p1 += __shfl_down(p1, off, 32);
            p2 += __shfl_down(p2, off, 32);
        }
        if (t == 0) { es2[i] = p1; ed2[i] = p2; }
    }
}

// ---------------- attention layer 2 -> z (split bf16 out), 4 rows per block ----------------
__global__ __launch_bounds__(256, 8) void k_attn2(const int* __restrict__ nbr, const int* __restrict__ cnt,
                                                  const float* __restrict__ es2, const float* __restrict__ ed2,
                                                  const float* __restrict__ Wh2,
                                                  unsigned short* __restrict__ zh, unsigned short* __restrict__ zl) {
    __shared__ float att[4][CAP];
    __shared__ int col[4][CAP];
    int w = threadIdx.x >> 6, l = threadIdx.x & 63;
    int i = blockIdx.x * 4 + w;
    int c = cnt[i];
    if (c == 0) {
        if (l < LAT) {
            float s = 0.f;
            for (int r = 0; r < NN; ++r) s += Wh2[(size_t)r * LAT + l];
            unsigned short hi, lo;
            split_bf16(elu_f(s * (1.0f / NN)), hi, lo);
            zh[(size_t)i * LAT + l] = hi;
            zl[(size_t)i * LAT + l] = lo;
        }
        return;
    }
    float esi = es2[i];
    const int* nb = nbr + (size_t)i * CAP;
    float m = -3.0e38f;
    for (int j = l; j < c; j += 64) {
        int cj = nb[j];
        col[w][j] = cj;
        float e = lrelu_f(esi + ed2[cj]);
        att[w][j] = e;
        m = fmaxf(m, e);
    }
    #pragma unroll
    for (int off = 32; off; off >>= 1) m = fmaxf(m, __shfl_down(m, off));
    m = __shfl(m, 0);
    float s = 0.f;
    for (int j = l; j < c; j += 64) {
        float p = __expf(att[w][j] - m);
        att[w][j] = p;
        s += p;
    }
    #pragma unroll
    for (int off = 32; off; off >>= 1) s += __shfl_down(s, off);
    s = __shfl(s, 0);
    if (l < LAT) {
        float inv = 1.0f / s;
        float a0 = 0.f, a1 = 0.f, a2 = 0.f, a3 = 0.f;
        int j = 0;
        for (; j + 4 <= c; j += 4) {
            a0 = fmaf(att[w][j + 0], Wh2[(size_t)col[w][j + 0] * LAT + l], a0);
            a1 = fmaf(att[w][j + 1], Wh2[(size_t)col[w][j + 1] * LAT + l], a1);
            a2 = fmaf(att[w][j + 2], Wh2[(size_t)col[w][j + 2] * LAT + l], a2);
            a3 = fmaf(att[w][j + 3], Wh2[(size_t)col[w][j + 3] * LAT + l], a3);
        }
        for (; j < c; ++j)
            a0 = fmaf(att[w][j], Wh2[(size_t)col[w][j] * LAT + l], a0);
        unsigned short hi, lo;
        split_bf16(elu_f(((a0 + a1) + (a2 + a3)) * inv), hi, lo);
        zh[(size_t)i * LAT + l] = hi;
        zl[(size_t)i * LAT + l] = lo;
    }
}

// ---------------- out = sigmoid(z @ z^T) via split-bf16 MFMA ----------------
// Symmetric output: each lane's 4 accumulator values (4 rows x 1 col) are stored
// TRANSPOSED as one float4 (1 row x 4 cols) — coalesced dwordx4 stores.
__global__ __launch_bounds__(256, 8) void k_zzt(const unsigned short* __restrict__ zh,
                                                const unsigned short* __restrict__ zl,
                                                float* __restrict__ out) {
    int t = threadIdx.x, w = t >> 6, l = t & 63;
    int m0 = blockIdx.y * 64 + w * 16;
    int n0 = blockIdx.x * 64;
    int r = l & 15, kg = (l >> 4) * 8;   // lane row-in-tile, k-group of 8
    bf16x8 ah = *(const bf16x8*)(zh + (size_t)(m0 + r) * LAT + kg);
    bf16x8 al = *(const bf16x8*)(zl + (size_t)(m0 + r) * LAT + kg);
    int mbase = m0 + (l >> 4) * 4;       // 4 consecutive C-rows this lane owns
    #pragma unroll
    for (int jp = 0; jp < 2; ++jp) {
        int nbA = n0 + (jp * 2 + 0) * 16;
        int nbB = n0 + (jp * 2 + 1) * 16;
        bf16x8 bhA = *(const bf16x8*)(zh + (size_t)(nbA + r) * LAT + kg);
        bf16x8 blA = *(const bf16x8*)(zl + (size_t)(nbA + r) * LAT + kg);
        bf16x8 bhB = *(const bf16x8*)(zh + (size_t)(nbB + r) * LAT + kg);
        bf16x8 blB = *(const bf16x8*)(zl + (size_t)(nbB + r) * LAT + kg);
        f32x4 accA = {0.f, 0.f, 0.f, 0.f};
        accA = __builtin_amdgcn_mfma_f32_16x16x32_bf16(ah, bhA, accA, 0, 0, 0);
        accA = __builtin_amdgcn_mfma_f32_16x16x32_bf16(ah, blA, accA, 0, 0, 0);
        accA = __builtin_amdgcn_mfma_f32_16x16x32_bf16(al, bhA, accA, 0, 0, 0);
        f32x4 accB = {0.f, 0.f, 0.f, 0.f};
        accB = __builtin_amdgcn_mfma_f32_16x16x32_bf16(ah, bhB, accB, 0, 0, 0);
        accB = __builtin_amdgcn_mfma_f32_16x16x32_bf16(ah, blB, accB, 0, 0, 0);
        accB = __builtin_amdgcn_mfma_f32_16x16x32_bf16(al, bhB, accB, 0, 0, 0);
        float4 oA, oB;
        oA.x = 1.0f / (1.0f + __expf(-accA[0]));
        oA.y = 1.0f / (1.0f + __expf(-accA[1]));
        oA.z = 1.0f / (1.0f + __expf(-accA[2]));
        oA.w = 1.0f / (1.0f + __expf(-accA[3]));
        oB.x = 1.0f / (1.0f + __expf(-accB[0]));
        oB.y = 1.0f / (1.0f + __expf(-accB[1]));
        oB.z = 1.0f / (1.0f + __expf(-accB[2]));
        oB.w = 1.0f / (1.0f + __expf(-accB[3]));
        // transposed store via symmetry: out[col][mbase..mbase+3]
        *(float4*)(out + (size_t)(nbA + (l & 15)) * NN + mbase) = oA;
        *(float4*)(out + (size_t)(nbB + (l & 15)) * NN + mbase) = oB;
    }
}

extern "C" void kernel_launch(void* const* d_in, const int* in_sizes, int n_in,
                              void* d_out, int out_size, void* d_ws, size_t ws_size,
                              hipStream_t stream) {
    const float* x      = (const float*)d_in[0];
    const float* A      = (const float*)d_in[1];
    const float* Wheads = (const float*)d_in[2];
    const float* aheads = (const float*)d_in[3];
    const float* Wout   = (const float*)d_in[4];
    const float* aout   = (const float*)d_in[5];
    float* out = (float*)d_out;

    char* ws = (char*)d_ws;
    size_t o = 0;
    auto alloc = [&](size_t bytes) { void* p = ws + o; o += (bytes + 255) & ~(size_t)255; return p; };
    int*   nbr   = (int*)  alloc((size_t)NN * CAP * 4);
    int*   cnt   = (int*)  alloc((size_t)NN * 4);
    float* Wh    = (float*)alloc((size_t)NN * HEADS * HID * 4);
    float* es    = (float*)alloc((size_t)HEADS * NN * 4);
    float* ed    = (float*)alloc((size_t)HEADS * NN * 4);
    float* Wh2   = (float*)alloc((size_t)NN * LAT * 4);
    float* es2   = (float*)alloc((size_t)NN * 4);
    float* ed2   = (float*)alloc((size_t)NN * 4);
    unsigned short* zh = (unsigned short*)alloc((size_t)NN * LAT * 2);
    unsigned short* zl = (unsigned short*)alloc((size_t)NN * LAT * 2);

    k_gemm1   <<<(NN / 64) * HEADS, 256, 0, stream>>>(x, Wheads, aheads, Wh, es, ed);
    k_rowattn <<<NN, 256, 0, stream>>>(A, nbr, cnt, es, ed, Wh, Wout, aout, Wh2, es2, ed2);
    k_attn2   <<<NN / 4, 256, 0, stream>>>(nbr, cnt, es2, ed2, Wh2, zh, zl);
    k_zzt     <<<dim3(NN / 64, NN / 64), 256, 0, stream>>>(zh, zl, out);
}

// Round 10
// 115.411 us; speedup vs baseline: 1.1478x; 1.1478x over previous
//
#include <hip/hip_runtime.h>
#include <hip/hip_bf16.h>

#define NN 6144
#define IN_DIM 256
#define HID 64
#define HEADS 4
#define LAT 32
#define CAP 192
#define ALPHA 0.2f
#define GEMM_BLOCKS 384                  // (NN/64) * HEADS

typedef __attribute__((ext_vector_type(8))) short bf16x8;
typedef __attribute__((ext_vector_type(4))) float f32x4;

__device__ __forceinline__ float elu_f(float v)   { return v > 0.f ? v : expm1f(v); }
__device__ __forceinline__ float lrelu_f(float v) { return v > 0.f ? v : ALPHA * v; }

__device__ __forceinline__ void split_bf16(float v, unsigned short& hi, unsigned short& lo) {
    unsigned u = __builtin_bit_cast(unsigned, v);
    hi = (unsigned short)(u >> 16);
    float vh = __builtin_bit_cast(float, u & 0xFFFF0000u);
    float rl = v - vh;                       // exact
    lo = (unsigned short)(__builtin_bit_cast(unsigned, rl) >> 16);
}
__device__ __forceinline__ unsigned short f2bf(float f) {      // round-to-nearest-even
    unsigned u = __builtin_bit_cast(unsigned, f);
    return (unsigned short)((u + 0x7FFFu + ((u >> 16) & 1u)) >> 16);
}
__device__ __forceinline__ float bf2f(unsigned short b) {
    return __builtin_bit_cast(float, (unsigned)b << 16);
}

// ---------------- k_pre: gemm1(+es/ed epilogue, bf16 Wh out) blocks first, then A-scan ----------------
__global__ __launch_bounds__(256) void k_pre(const float* __restrict__ A,
                                             const float* __restrict__ x,
                                             const float* __restrict__ Wheads,
                                             const float* __restrict__ aheads,
                                             int* __restrict__ nbr, int* __restrict__ cnt,
                                             unsigned short* __restrict__ Whb,
                                             float* __restrict__ es, float* __restrict__ ed) {
    __shared__ __align__(16) float smem[2048];   // 8 KB
    int bid = blockIdx.x;
    int t = threadIdx.x;
    if (bid < GEMM_BLOCKS) {
        int head = bid & 3, m0 = (bid >> 2) * 64;
        float (*As)[64] = (float(*)[64])smem;
        float (*Bs)[64] = (float(*)[64])(smem + 1024);
        const float* Wc = Wheads + (size_t)head * IN_DIM * HID;
        int ty = t >> 4, tx = t & 15;
        float acc[4][4] = {};
        for (int k0 = 0; k0 < IN_DIM; k0 += 16) {
            {
                int row = t >> 2, k4 = (t & 3) * 4;
                float4 v = *(const float4*)(x + (size_t)(m0 + row) * IN_DIM + k0 + k4);
                As[k4 + 0][row] = v.x; As[k4 + 1][row] = v.y;
                As[k4 + 2][row] = v.z; As[k4 + 3][row] = v.w;
                int kk = t >> 4, n4 = (t & 15) * 4;
                *(float4*)&Bs[kk][n4] = *(const float4*)(Wc + (size_t)(k0 + kk) * HID + n4);
            }
            __syncthreads();
            #pragma unroll
            for (int k = 0; k < 16; ++k) {
                float4 av = *(float4*)&As[k][ty * 4];
                float4 bv = *(float4*)&Bs[k][tx * 4];
                float ar[4] = {av.x, av.y, av.z, av.w};
                float br[4] = {bv.x, bv.y, bv.z, bv.w};
                #pragma unroll
                for (int i = 0; i < 4; ++i)
                    #pragma unroll
                    for (int j = 0; j < 4; ++j)
                        acc[i][j] = fmaf(ar[i], br[j], acc[i][j]);
            }
            __syncthreads();
        }
        #pragma unroll
        for (int i = 0; i < 4; ++i) {
            ushort4 o;
            o.x = f2bf(acc[i][0]); o.y = f2bf(acc[i][1]);
            o.z = f2bf(acc[i][2]); o.w = f2bf(acc[i][3]);
            *(ushort4*)(Whb + (size_t)(m0 + ty * 4 + i) * (HEADS * HID) + head * HID + tx * 4) = o;
        }
        float4 a1v = *(const float4*)(aheads + head * 2 * HID + tx * 4);
        float4 a2v = *(const float4*)(aheads + head * 2 * HID + HID + tx * 4);
        #pragma unroll
        for (int i = 0; i < 4; ++i) {
            float p1 = acc[i][0] * a1v.x + acc[i][1] * a1v.y + acc[i][2] * a1v.z + acc[i][3] * a1v.w;
            float p2 = acc[i][0] * a2v.x + acc[i][1] * a2v.y + acc[i][2] * a2v.z + acc[i][3] * a2v.w;
            #pragma unroll
            for (int off = 8; off; off >>= 1) {
                p1 += __shfl_down(p1, off, 16);
                p2 += __shfl_down(p2, off, 16);
            }
            if (tx == 0) {
                es[head * NN + m0 + ty * 4 + i] = p1;
                ed[head * NN + m0 + ty * 4 + i] = p2;
            }
        }
    } else {
        int row = bid - GEMM_BLOCKS;
        int* lcnt = (int*)smem;
        const float4* Arow = (const float4*)(A + (size_t)row * NN);
        if (t == 0) *lcnt = 0;
        __syncthreads();
        int* my = nbr + (size_t)row * CAP;
        #pragma unroll
        for (int it = 0; it < NN / 4 / 256; ++it) {
            int idx4 = it * 256 + t;
            float4 v = Arow[idx4];
            int base = idx4 * 4;
            if (v.x != 0.f) { int p = atomicAdd(lcnt, 1); if (p < CAP) my[p] = base; }
            if (v.y != 0.f) { int p = atomicAdd(lcnt, 1); if (p < CAP) my[p] = base + 1; }
            if (v.z != 0.f) { int p = atomicAdd(lcnt, 1); if (p < CAP) my[p] = base + 2; }
            if (v.w != 0.f) { int p = atomicAdd(lcnt, 1); if (p < CAP) my[p] = base + 3; }
        }
        __syncthreads();
        if (t == 0) cnt[row] = *lcnt < CAP ? *lcnt : CAP;
    }
}

// ---------------- k_attn1g2: attn layer 1 (4 waves = 4 heads) + fused gemm2/e2; bf16 Wh gather ----------------
__global__ __launch_bounds__(256, 8) void k_attn1g2(const int* __restrict__ nbr, const int* __restrict__ cnt,
                                                    const float* __restrict__ es, const float* __restrict__ ed,
                                                    const unsigned short* __restrict__ Whb,
                                                    const float* __restrict__ Wout, const float* __restrict__ aout,
                                                    float* __restrict__ Wh2,
                                                    float* __restrict__ es2, float* __restrict__ ed2) {
    __shared__ int col[CAP];
    __shared__ float att[HEADS][CAP];
    __shared__ float hrow[HEADS * HID];
    __shared__ float part[8][LAT];
    int i = blockIdx.x;
    int t = threadIdx.x, h = t >> 6, l = t & 63;
    int c = cnt[i];
    float hval;
    if (c == 0) {
        float s = 0.f;
        for (int r = 0; r < NN; ++r) s += bf2f(Whb[(size_t)r * (HEADS * HID) + h * HID + l]);
        hval = elu_f(s * (1.0f / NN));
    } else {
        const int* nb = nbr + (size_t)i * CAP;
        float esi = es[h * NN + i];
        float m = -3.0e38f;
        for (int j = l; j < c; j += 64) {
            int cj = nb[j];
            if (h == 0) col[j] = cj;
            float e = lrelu_f(esi + ed[h * NN + cj]);
            att[h][j] = e;
            m = fmaxf(m, e);
        }
        #pragma unroll
        for (int off = 32; off; off >>= 1) m = fmaxf(m, __shfl_down(m, off));
        m = __shfl(m, 0);
        float s = 0.f;
        for (int j = l; j < c; j += 64) {
            float p = __expf(att[h][j] - m);
            att[h][j] = p;
            s += p;
        }
        #pragma unroll
        for (int off = 32; off; off >>= 1) s += __shfl_down(s, off);
        s = __shfl(s, 0);
        __syncthreads();          // col[] + att[h][] visible to all
        float inv = 1.0f / s;
        const unsigned short* WhH = Whb + h * HID + l;
        float a0 = 0.f, a1 = 0.f, a2 = 0.f, a3 = 0.f;
        float a4 = 0.f, a5 = 0.f, a6 = 0.f, a7 = 0.f;
        int j = 0;
        for (; j + 8 <= c; j += 8) {
            a0 = fmaf(att[h][j + 0], bf2f(WhH[(size_t)col[j + 0] * (HEADS * HID)]), a0);
            a1 = fmaf(att[h][j + 1], bf2f(WhH[(size_t)col[j + 1] * (HEADS * HID)]), a1);
            a2 = fmaf(att[h][j + 2], bf2f(WhH[(size_t)col[j + 2] * (HEADS * HID)]), a2);
            a3 = fmaf(att[h][j + 3], bf2f(WhH[(size_t)col[j + 3] * (HEADS * HID)]), a3);
            a4 = fmaf(att[h][j + 4], bf2f(WhH[(size_t)col[j + 4] * (HEADS * HID)]), a4);
            a5 = fmaf(att[h][j + 5], bf2f(WhH[(size_t)col[j + 5] * (HEADS * HID)]), a5);
            a6 = fmaf(att[h][j + 6], bf2f(WhH[(size_t)col[j + 6] * (HEADS * HID)]), a6);
            a7 = fmaf(att[h][j + 7], bf2f(WhH[(size_t)col[j + 7] * (HEADS * HID)]), a7);
        }
        for (; j < c; ++j)
            a0 = fmaf(att[h][j], bf2f(WhH[(size_t)col[j] * (HEADS * HID)]), a0);
        hval = elu_f((((a0 + a1) + (a2 + a3)) + ((a4 + a5) + (a6 + a7))) * inv);
    }
    hrow[h * HID + l] = hval;
    __syncthreads();
    {
        int half = l >> 5, cc = l & 31;
        int tbase = h * HID + half * 32;
        float p = 0.f;
        #pragma unroll 8
        for (int tt = 0; tt < 32; ++tt)
            p = fmaf(hrow[tbase + tt], Wout[(tbase + tt) * LAT + cc], p);
        part[h * 2 + half][cc] = p;
    }
    __syncthreads();
    if (t < 32) {
        float acc = 0.f;
        #pragma unroll
        for (int w = 0; w < 8; ++w) acc += part[w][t];
        Wh2[(size_t)i * LAT + t] = acc;
        float p1 = acc * aout[t], p2 = acc * aout[LAT + t];
        #pragma unroll
        for (int off = 16; off; off >>= 1) {
            p1 += __shfl_down(p1, off, 32);
            p2 += __shfl_down(p2, off, 32);
        }
        if (t == 0) { es2[i] = p1; ed2[i] = p2; }
    }
}

// ---------------- attention layer 2 -> z (split bf16 out), 4 rows per block ----------------
__global__ __launch_bounds__(256, 8) void k_attn2(const int* __restrict__ nbr, const int* __restrict__ cnt,
                                                  const float* __restrict__ es2, const float* __restrict__ ed2,
                                                  const float* __restrict__ Wh2,
                                                  unsigned short* __restrict__ zh, unsigned short* __restrict__ zl) {
    __shared__ float att[4][CAP];
    __shared__ int col[4][CAP];
    int w = threadIdx.x >> 6, l = threadIdx.x & 63;
    int i = blockIdx.x * 4 + w;
    int c = cnt[i];
    if (c == 0) {
        if (l < LAT) {
            float s = 0.f;
            for (int r = 0; r < NN; ++r) s += Wh2[(size_t)r * LAT + l];
            unsigned short hi, lo;
            split_bf16(elu_f(s * (1.0f / NN)), hi, lo);
            zh[(size_t)i * LAT + l] = hi;
            zl[(size_t)i * LAT + l] = lo;
        }
        return;
    }
    float esi = es2[i];
    const int* nb = nbr + (size_t)i * CAP;
    float m = -3.0e38f;
    for (int j = l; j < c; j += 64) {
        int cj = nb[j];
        col[w][j] = cj;
        float e = lrelu_f(esi + ed2[cj]);
        att[w][j] = e;
        m = fmaxf(m, e);
    }
    #pragma unroll
    for (int off = 32; off; off >>= 1) m = fmaxf(m, __shfl_down(m, off));
    m = __shfl(m, 0);
    float s = 0.f;
    for (int j = l; j < c; j += 64) {
        float p = __expf(att[w][j] - m);
        att[w][j] = p;
        s += p;
    }
    #pragma unroll
    for (int off = 32; off; off >>= 1) s += __shfl_down(s, off);
    s = __shfl(s, 0);
    if (l < LAT) {
        float inv = 1.0f / s;
        float a0 = 0.f, a1 = 0.f, a2 = 0.f, a3 = 0.f;
        int j = 0;
        for (; j + 4 <= c; j += 4) {
            a0 = fmaf(att[w][j + 0], Wh2[(size_t)col[w][j + 0] * LAT + l], a0);
            a1 = fmaf(att[w][j + 1], Wh2[(size_t)col[w][j + 1] * LAT + l], a1);
            a2 = fmaf(att[w][j + 2], Wh2[(size_t)col[w][j + 2] * LAT + l], a2);
            a3 = fmaf(att[w][j + 3], Wh2[(size_t)col[w][j + 3] * LAT + l], a3);
        }
        for (; j < c; ++j)
            a0 = fmaf(att[w][j], Wh2[(size_t)col[w][j] * LAT + l], a0);
        unsigned short hi, lo;
        split_bf16(elu_f(((a0 + a1) + (a2 + a3)) * inv), hi, lo);
        zh[(size_t)i * LAT + l] = hi;
        zl[(size_t)i * LAT + l] = lo;
    }
}

// ---------------- out = sigmoid(z @ z^T) via split-bf16 MFMA, symmetric float4 stores ----------------
__global__ __launch_bounds__(256, 8) void k_zzt(const unsigned short* __restrict__ zh,
                                                const unsigned short* __restrict__ zl,
                                                float* __restrict__ out) {
    int t = threadIdx.x, w = t >> 6, l = t & 63;
    int m0 = blockIdx.y * 64 + w * 16;
    int n0 = blockIdx.x * 64;
    int r = l & 15, kg = (l >> 4) * 8;   // lane row-in-tile, k-group of 8
    bf16x8 ah = *(const bf16x8*)(zh + (size_t)(m0 + r) * LAT + kg);
    bf16x8 al = *(const bf16x8*)(zl + (size_t)(m0 + r) * LAT + kg);
    int mbase = m0 + (l >> 4) * 4;       // 4 consecutive C-rows this lane owns
    #pragma unroll
    for (int jp = 0; jp < 2; ++jp) {
        int nbA = n0 + (jp * 2 + 0) * 16;
        int nbB = n0 + (jp * 2 + 1) * 16;
        bf16x8 bhA = *(const bf16x8*)(zh + (size_t)(nbA + r) * LAT + kg);
        bf16x8 blA = *(const bf16x8*)(zl + (size_t)(nbA + r) * LAT + kg);
        bf16x8 bhB = *(const bf16x8*)(zh + (size_t)(nbB + r) * LAT + kg);
        bf16x8 blB = *(const bf16x8*)(zl + (size_t)(nbB + r) * LAT + kg);
        f32x4 accA = {0.f, 0.f, 0.f, 0.f};
        accA = __builtin_amdgcn_mfma_f32_16x16x32_bf16(ah, bhA, accA, 0, 0, 0);
        accA = __builtin_amdgcn_mfma_f32_16x16x32_bf16(ah, blA, accA, 0, 0, 0);
        accA = __builtin_amdgcn_mfma_f32_16x16x32_bf16(al, bhA, accA, 0, 0, 0);
        f32x4 accB = {0.f, 0.f, 0.f, 0.f};
        accB = __builtin_amdgcn_mfma_f32_16x16x32_bf16(ah, bhB, accB, 0, 0, 0);
        accB = __builtin_amdgcn_mfma_f32_16x16x32_bf16(ah, blB, accB, 0, 0, 0);
        accB = __builtin_amdgcn_mfma_f32_16x16x32_bf16(al, bhB, accB, 0, 0, 0);
        float4 oA, oB;
        oA.x = 1.0f / (1.0f + __expf(-accA[0]));
        oA.y = 1.0f / (1.0f + __expf(-accA[1]));
        oA.z = 1.0f / (1.0f + __expf(-accA[2]));
        oA.w = 1.0f / (1.0f + __expf(-accA[3]));
        oB.x = 1.0f / (1.0f + __expf(-accB[0]));
        oB.y = 1.0f / (1.0f + __expf(-accB[1]));
        oB.z = 1.0f / (1.0f + __expf(-accB[2]));
        oB.w = 1.0f / (1.0f + __expf(-accB[3]));
        // transposed store via output symmetry: out[col][mbase..mbase+3]
        *(float4*)(out + (size_t)(nbA + (l & 15)) * NN + mbase) = oA;
        *(float4*)(out + (size_t)(nbB + (l & 15)) * NN + mbase) = oB;
    }
}

extern "C" void kernel_launch(void* const* d_in, const int* in_sizes, int n_in,
                              void* d_out, int out_size, void* d_ws, size_t ws_size,
                              hipStream_t stream) {
    const float* x      = (const float*)d_in[0];
    const float* A      = (const float*)d_in[1];
    const float* Wheads = (const float*)d_in[2];
    const float* aheads = (const float*)d_in[3];
    const float* Wout   = (const float*)d_in[4];
    const float* aout   = (const float*)d_in[5];
    float* out = (float*)d_out;

    char* ws = (char*)d_ws;
    size_t o = 0;
    auto alloc = [&](size_t bytes) { void* p = ws + o; o += (bytes + 255) & ~(size_t)255; return p; };
    int*   nbr   = (int*)  alloc((size_t)NN * CAP * 4);
    int*   cnt   = (int*)  alloc((size_t)NN * 4);
    unsigned short* Whb = (unsigned short*)alloc((size_t)NN * HEADS * HID * 2);
    float* es    = (float*)alloc((size_t)HEADS * NN * 4);
    float* ed    = (float*)alloc((size_t)HEADS * NN * 4);
    float* Wh2   = (float*)alloc((size_t)NN * LAT * 4);
    float* es2   = (float*)alloc((size_t)NN * 4);
    float* ed2   = (float*)alloc((size_t)NN * 4);
    unsigned short* zh = (unsigned short*)alloc((size_t)NN * LAT * 2);
    unsigned short* zl = (unsigned short*)alloc((size_t)NN * LAT * 2);

    k_pre     <<<GEMM_BLOCKS + NN, 256, 0, stream>>>(A, x, Wheads, aheads, nbr, cnt, Whb, es, ed);
    k_attn1g2 <<<NN, 256, 0, stream>>>(nbr, cnt, es, ed, Whb, Wout, aout, Wh2, es2, ed2);
    k_attn2   <<<NN / 4, 256, 0, stream>>>(nbr, cnt, es2, ed2, Wh2, zh, zl);
    k_zzt     <<<dim3(NN / 64, NN / 64), 256, 0, stream>>>(zh, zl, out);
}